// Round 11
// baseline (74.263 us; speedup 1.0000x reference)
//
#include <hip/hip_runtime.h>

#define BATCH 16384
#define NPTS  500
#define NOBJ  30
#define EPW   2    // batch elements per wave
#define WPB   4    // waves per block
#define NBLK  (BATCH / (EPW * WPB))   // 2048 blocks = 8 blocks/CU = 32 waves/CU
#define NGRP  32                      // contiguous groups of 64 blocks
#define GRP   (NBLK / NGRP)           // 64 blocks per group
#define CTR_STRIDE 32                 // uints between l1 counters = 128 B

typedef float v2f __attribute__((ext_vector_type(2)));

// raw v_sqrt_f32 (1 ULP), no IEEE denormal-fixup sequence
__device__ __forceinline__ float fsqrt(float x) {
    return __builtin_amdgcn_sqrtf(x);
}

// d_ws is re-poisoned to 0xAA bytes before EVERY launch (documented harness
// behavior; empirically confirmed R9/R10 incl. under rocprof replay), so
// every counter starts at exactly 0xAAAAAAAA.
#define CTR_INIT 0xAAAAAAAAu

__global__ __launch_bounds__(256, 8) void add_loss_fused(
    const float* __restrict__ pred_r,   // (B,4)
    const float* __restrict__ pred_t,   // (B,3)
    const float* __restrict__ gt_r,     // (B,4)
    const float* __restrict__ gt_t,     // (B,3)
    const int*   __restrict__ obj_ids,  // (B,)
    const float* __restrict__ points,   // (NOBJ, NPTS, 3)
    float*        __restrict__ partial, // (NBLK,) in d_ws
    unsigned int* __restrict__ ctr1,    // NGRP counters, 128B apart, in d_ws
    unsigned int* __restrict__ ctr2,    // 1 counter (own line) in d_ws
    float*        __restrict__ gsum,    // (NGRP,) group sums in d_ws
    float*        __restrict__ out)     // scalar
{
    const int wave = threadIdx.x >> 6;
    const int lane = threadIdx.x & 63;
    const int b0   = (blockIdx.x * WPB + wave) * EPW;

    const float mask1 = (lane < 61) ? 1.0f : 0.0f;  // 500 = 64*4 + 61*4 groups
    const int   g1    = min(64 + lane, 124);        // clamped 2nd point-group

    float acc_pts   = 0.0f;
    float acc_trans = 0.0f;

    #pragma unroll
    for (int e = 0; e < EPW; ++e) {
        const int b = b0 + e;

        // --- issue ALL loads for this element up front ---
        const float4 qp = ((const float4*)pred_r)[b];
        const float4 qg = ((const float4*)gt_r)[b];
        const float  tpx = pred_t[3*b+0], tpy = pred_t[3*b+1], tpz = pred_t[3*b+2];
        const float  tgx = gt_t[3*b+0],   tgy = gt_t[3*b+1],   tgz = gt_t[3*b+2];
        const int    obj = obj_ids[b];
        // object row = 1500 floats = 6000 B (16-divisible -> float4-aligned)
        const float4* __restrict__ P4 = (const float4*)(points + (size_t)obj * (NPTS*3));
        const float4 A0 = P4[3*lane+0], B0 = P4[3*lane+1], C0 = P4[3*lane+2];
        const float4 A1 = P4[3*g1+0],   B1 = P4[3*g1+1],   C1 = P4[3*g1+2];

        // --- coefficient VALU overlaps the point-load latency ---
        v2f W = {qp.x, qg.x}, X = {qp.y, qg.y}, Y = {qp.z, qg.z}, Z = {qp.w, qg.w};
        v2f t00 = Y*Y + Z*Z;
        v2f t01 = X*Y - W*Z;
        v2f t02 = X*Z + W*Y;
        v2f t10 = X*Y + W*Z;
        v2f t11 = X*X + Z*Z;
        v2f t12 = Y*Z - W*X;
        v2f t20 = X*Z - W*Y;
        v2f t21 = Y*Z + W*X;
        v2f t22 = X*X + Y*Y;
        float d00 = 2.f*(t00.y - t00.x);
        float d01 = 2.f*(t01.x - t01.y);
        float d02 = 2.f*(t02.x - t02.y);
        float d10 = 2.f*(t10.x - t10.y);
        float d11 = 2.f*(t11.y - t11.x);
        float d12 = 2.f*(t12.x - t12.y);
        float d20 = 2.f*(t20.x - t20.y);
        float d21 = 2.f*(t21.x - t21.y);
        float d22 = 2.f*(t22.y - t22.x);
        float tdx = tpx - tgx, tdy = tpy - tgy, tdz = tpz - tgz;

        // --- group 0: full weight ---
        float s = 0.0f;
        {
            v2f xs[2] = { {A0.x, A0.w}, {B0.z, C0.y} };
            v2f ys[2] = { {A0.y, B0.x}, {B0.w, C0.z} };
            v2f zs[2] = { {A0.z, B0.y}, {C0.x, C0.w} };
            #pragma unroll
            for (int j = 0; j < 2; ++j) {
                v2f x = xs[j], y = ys[j], z = zs[j];
                v2f vx = d00*x + d01*y + d02*z;
                v2f vy = d10*x + d11*y + d12*z;
                v2f vz = d20*x + d21*y + d22*z;
                v2f r  = vx*vx + vy*vy + vz*vz;
                s += fsqrt(r.x) + fsqrt(r.y);
                v2f ax = vx + tdx, ay = vy + tdy, az = vz + tdz;
                v2f r2 = ax*ax + ay*ay + az*az;
                s += fsqrt(r2.x) + fsqrt(r2.y);
            }
        }
        // --- group 1: masked (lanes 61-63 read clamped-valid data, ×0) ---
        {
            float s1 = 0.0f;
            v2f xs[2] = { {A1.x, A1.w}, {B1.z, C1.y} };
            v2f ys[2] = { {A1.y, B1.x}, {B1.w, C1.z} };
            v2f zs[2] = { {A1.z, B1.y}, {C1.x, C1.w} };
            #pragma unroll
            for (int j = 0; j < 2; ++j) {
                v2f x = xs[j], y = ys[j], z = zs[j];
                v2f vx = d00*x + d01*y + d02*z;
                v2f vy = d10*x + d11*y + d12*z;
                v2f vz = d20*x + d21*y + d22*z;
                v2f r  = vx*vx + vy*vy + vz*vz;
                s1 += fsqrt(r.x) + fsqrt(r.y);
                v2f ax = vx + tdx, ay = vy + tdy, az = vz + tdz;
                v2f r2 = ax*ax + ay*ay + az*az;
                s1 += fsqrt(r2.x) + fsqrt(r2.y);
            }
            s += mask1 * s1;
        }

        acc_pts   += s;
        acc_trans += fsqrt(tdx*tdx + tdy*tdy + tdz*tdz);
    }

    // one butterfly per wave
    #pragma unroll
    for (int off = 32; off > 0; off >>= 1)
        acc_pts += __shfl_down(acc_pts, off, 64);

    __shared__ float red[WPB];
    __shared__ int   flag;
    if (lane == 0)
        red[wave] = acc_pts * (1.0f / NPTS) + acc_trans;
    if (threadIdx.x == 0) flag = 0;
    __syncthreads();

    const int grp = blockIdx.x >> 6;   // 64 contiguous blocks per group

    if (threadIdx.x == 0) {
        float bsum = red[0] + red[1] + red[2] + red[3];
        // agent-scope atomic store: visible at coherence point on completion
        __hip_atomic_store(&partial[blockIdx.x], bsum,
                           __ATOMIC_RELAXED, __HIP_MEMORY_SCOPE_AGENT);
        asm volatile("s_waitcnt vmcnt(0)" ::: "memory");
        unsigned int old = __hip_atomic_fetch_add(&ctr1[grp * CTR_STRIDE], 1u,
                              __ATOMIC_RELAXED, __HIP_MEMORY_SCOPE_AGENT);
        if (old == CTR_INIT + (unsigned)(GRP - 1)) flag = 1;
    }
    __syncthreads();

    // group winner: wave 0 reduces this group's 64 partials
    if (flag && wave == 0) {
        float v = __hip_atomic_load(&partial[grp * GRP + lane],
                                    __ATOMIC_RELAXED, __HIP_MEMORY_SCOPE_AGENT);
        #pragma unroll
        for (int off = 32; off > 0; off >>= 1)
            v += __shfl_down(v, off, 64);

        int lastall = 0;
        if (lane == 0) {
            __hip_atomic_store(&gsum[grp], v,
                               __ATOMIC_RELAXED, __HIP_MEMORY_SCOPE_AGENT);
            asm volatile("s_waitcnt vmcnt(0)" ::: "memory");
            unsigned int old2 = __hip_atomic_fetch_add(ctr2, 1u,
                                  __ATOMIC_RELAXED, __HIP_MEMORY_SCOPE_AGENT);
            lastall = (old2 == CTR_INIT + (unsigned)(NGRP - 1)) ? 1 : 0;
        }
        lastall = __shfl(lastall, 0, 64);

        // very last group winner: reduce the 32 group sums, write the scalar
        if (lastall) {
            float w = 0.0f;
            if (lane < NGRP)
                w = __hip_atomic_load(&gsum[lane],
                                      __ATOMIC_RELAXED, __HIP_MEMORY_SCOPE_AGENT);
            #pragma unroll
            for (int off = 32; off > 0; off >>= 1)
                w += __shfl_down(w, off, 64);
            if (lane == 0)
                out[0] = w * (1.0f / BATCH);
        }
    }
}

extern "C" void kernel_launch(void* const* d_in, const int* in_sizes, int n_in,
                              void* d_out, int out_size, void* d_ws, size_t ws_size,
                              hipStream_t stream) {
    const float* pred_r  = (const float*)d_in[0];
    const float* pred_t  = (const float*)d_in[1];
    const float* gt_r    = (const float*)d_in[2];
    const float* gt_t    = (const float*)d_in[3];
    const int*   obj_ids = (const int*)d_in[4];
    const float* points  = (const float*)d_in[5];
    float* out = (float*)d_out;

    // ws layout: [0,8K) partials | [8K,12K) l1 ctrs | [12K) l2 ctr | [12K+128) gsum
    char* ws = (char*)d_ws;
    float*        partial = (float*)ws;
    unsigned int* ctr1    = (unsigned int*)(ws + NBLK * sizeof(float));
    unsigned int* ctr2    = (unsigned int*)(ws + NBLK * sizeof(float)
                                            + NGRP * CTR_STRIDE * sizeof(unsigned int));
    float*        gsum    = (float*)(ws + NBLK * sizeof(float)
                                     + NGRP * CTR_STRIDE * sizeof(unsigned int) + 128);

    add_loss_fused<<<NBLK, 256, 0, stream>>>(
        pred_r, pred_t, gt_r, gt_t, obj_ids, points, partial, ctr1, ctr2, gsum, out);
}

// Round 12
// 72.770 us; speedup vs baseline: 1.0205x; 1.0205x over previous
//
#include <hip/hip_runtime.h>

#define BATCH 16384
#define NPTS  500
#define NOBJ  30
#define EPW   2    // batch elements per wave
#define WPB   4    // waves per block
#define NBLK  (BATCH / (EPW * WPB))   // 2048 blocks = 8 blocks/CU = 32 waves/CU

typedef float v2f __attribute__((ext_vector_type(2)));

// raw v_sqrt_f32 (1 ULP), no IEEE denormal-fixup sequence
__device__ __forceinline__ float fsqrt(float x) {
    return __builtin_amdgcn_sqrtf(x);
}

__global__ __launch_bounds__(256) void add_loss_stage1(
    const float* __restrict__ pred_r,   // (B,4)
    const float* __restrict__ pred_t,   // (B,3)
    const float* __restrict__ gt_r,     // (B,4)
    const float* __restrict__ gt_t,     // (B,3)
    const int*   __restrict__ obj_ids,  // (B,)
    const float* __restrict__ points,   // (NOBJ, NPTS, 3)
    float* __restrict__ partial)        // (NBLK,)
{
    const int wave  = threadIdx.x >> 6;
    const int lane  = threadIdx.x & 63;
    const int gwave = blockIdx.x * WPB + wave;
    const int b0    = gwave * EPW;

    float acc_pts   = 0.0f;
    float acc_trans = 0.0f;

    #pragma unroll
    for (int e = 0; e < EPW; ++e) {
        const int b = b0 + e;

        const float4 qp = ((const float4*)pred_r)[b];
        const float4 qg = ((const float4*)gt_r)[b];

        // pack pred (.x) and gt (.y) quats -> packed term math (v_pk_*)
        v2f W = {qp.x, qg.x}, X = {qp.y, qg.y}, Y = {qp.z, qg.z}, Z = {qp.w, qg.w};
        v2f t00 = Y*Y + Z*Z;
        v2f t01 = X*Y - W*Z;
        v2f t02 = X*Z + W*Y;
        v2f t10 = X*Y + W*Z;
        v2f t11 = X*X + Z*Z;
        v2f t12 = Y*Z - W*X;
        v2f t20 = X*Z - W*Y;
        v2f t21 = Y*Z + W*X;
        v2f t22 = X*X + Y*Y;
        // diagonal: 2*(g-p); off-diag: 2*(p-g)
        float d00 = 2.f*(t00.y - t00.x);
        float d01 = 2.f*(t01.x - t01.y);
        float d02 = 2.f*(t02.x - t02.y);
        float d10 = 2.f*(t10.x - t10.y);
        float d11 = 2.f*(t11.y - t11.x);
        float d12 = 2.f*(t12.x - t12.y);
        float d20 = 2.f*(t20.x - t20.y);
        float d21 = 2.f*(t21.x - t21.y);
        float d22 = 2.f*(t22.y - t22.x);

        float tdx = pred_t[3*b+0] - gt_t[3*b+0];
        float tdy = pred_t[3*b+1] - gt_t[3*b+1];
        float tdz = pred_t[3*b+2] - gt_t[3*b+2];

        const int obj = obj_ids[b];
        // object row = 1500 floats = 6000 B (16-divisible -> float4-aligned)
        const float4* __restrict__ P4 = (const float4*)(points + (size_t)obj * (NPTS*3));

        float s = 0.0f;
        // 500 points = 125 groups of 4 points (3 float4 per group),
        // processed as packed pairs (v_pk_fma_f32 / v_pk_add_f32).
        #pragma unroll
        for (int t = 0; t < 2; ++t) {
            const int g = t*64 + lane;
            if (t == 0 || lane < 61) {
                float4 a  = P4[3*g+0];
                float4 b4 = P4[3*g+1];
                float4 c  = P4[3*g+2];
                v2f xs[2] = { {a.x, a.w},  {b4.z, c.y} };
                v2f ys[2] = { {a.y, b4.x}, {b4.w, c.z} };
                v2f zs[2] = { {a.z, b4.y}, {c.x, c.w} };
                #pragma unroll
                for (int j = 0; j < 2; ++j) {
                    v2f x = xs[j], y = ys[j], z = zs[j];
                    v2f vx = d00*x + d01*y + d02*z;
                    v2f vy = d10*x + d11*y + d12*z;
                    v2f vz = d20*x + d21*y + d22*z;
                    v2f r  = vx*vx + vy*vy + vz*vz;
                    s += fsqrt(r.x) + fsqrt(r.y);
                    v2f ax = vx + tdx, ay = vy + tdy, az = vz + tdz;
                    v2f r2 = ax*ax + ay*ay + az*az;
                    s += fsqrt(r2.x) + fsqrt(r2.y);
                }
            }
        }

        acc_pts   += s;
        acc_trans += fsqrt(tdx*tdx + tdy*tdy + tdz*tdz);
    }

    // one butterfly per wave
    #pragma unroll
    for (int off = 32; off > 0; off >>= 1)
        acc_pts += __shfl_down(acc_pts, off, 64);

    __shared__ float red[WPB];
    if (lane == 0)
        red[wave] = acc_pts * (1.0f / NPTS) + acc_trans;
    __syncthreads();
    if (threadIdx.x == 0)
        partial[blockIdx.x] = red[0] + red[1] + red[2] + red[3];  // plain store
}

__global__ __launch_bounds__(256) void add_loss_stage2(
    const float* __restrict__ partial,  // (NBLK,)
    float* __restrict__ out)            // scalar
{
    const int wave = threadIdx.x >> 6;
    const int lane = threadIdx.x & 63;

    float s = 0.0f;
    #pragma unroll
    for (int k = 0; k < NBLK / 256; ++k)
        s += partial[k * 256 + threadIdx.x];

    #pragma unroll
    for (int off = 32; off > 0; off >>= 1)
        s += __shfl_down(s, off, 64);

    __shared__ float red[4];
    if (lane == 0) red[wave] = s;
    __syncthreads();
    if (threadIdx.x == 0)
        out[0] = (red[0] + red[1] + red[2] + red[3]) * (1.0f / BATCH);
}

extern "C" void kernel_launch(void* const* d_in, const int* in_sizes, int n_in,
                              void* d_out, int out_size, void* d_ws, size_t ws_size,
                              hipStream_t stream) {
    const float* pred_r  = (const float*)d_in[0];
    const float* pred_t  = (const float*)d_in[1];
    const float* gt_r    = (const float*)d_in[2];
    const float* gt_t    = (const float*)d_in[3];
    const int*   obj_ids = (const int*)d_in[4];
    const float* points  = (const float*)d_in[5];
    float* out     = (float*)d_out;
    float* partial = (float*)d_ws;      // 2048 floats = 8 KB of scratch

    add_loss_stage1<<<NBLK, 256, 0, stream>>>(
        pred_r, pred_t, gt_r, gt_t, obj_ids, points, partial);
    add_loss_stage2<<<1, 256, 0, stream>>>(partial, out);
}

// Round 13
// 71.671 us; speedup vs baseline: 1.0362x; 1.0153x over previous
//
#include <hip/hip_runtime.h>

#define BATCH 16384
#define NPTS  500
#define NOBJ  30
#define EPW   2    // batch elements per wave
#define WPB   4    // waves per block
#define NBLK  (BATCH / (EPW * WPB))   // 2048 stage-1 blocks = 8 blocks/CU = 32 waves/CU

typedef float v2f __attribute__((ext_vector_type(2)));

// raw v_sqrt_f32 (1 ULP), no IEEE denormal-fixup sequence
__device__ __forceinline__ float fsqrt(float x) {
    return __builtin_amdgcn_sqrtf(x);
}

__global__ __launch_bounds__(256) void add_loss_stage1(
    const float* __restrict__ pred_r,   // (B,4)
    const float* __restrict__ pred_t,   // (B,3)
    const float* __restrict__ gt_r,     // (B,4)
    const float* __restrict__ gt_t,     // (B,3)
    const int*   __restrict__ obj_ids,  // (B,)
    const float* __restrict__ points,   // (NOBJ, NPTS, 3)
    float* __restrict__ partial)        // (NBLK,)
{
    const int wave  = threadIdx.x >> 6;
    const int lane  = threadIdx.x & 63;
    const int gwave = blockIdx.x * WPB + wave;
    const int b0    = gwave * EPW;

    float acc_pts   = 0.0f;
    float acc_trans = 0.0f;

    #pragma unroll
    for (int e = 0; e < EPW; ++e) {
        const int b = b0 + e;

        const float4 qp = ((const float4*)pred_r)[b];
        const float4 qg = ((const float4*)gt_r)[b];

        float pw=qp.x, px=qp.y, py=qp.z, pz=qp.w;
        float gw=qg.x, gx=qg.y, gy=qg.z, gz=qg.w;

        // D = Rp - Rg from unnormalized quats (paired differences)
        float d00 = 2.f*((gy*gy + gz*gz) - (py*py + pz*pz));
        float d01 = 2.f*((px*py - pw*pz) - (gx*gy - gw*gz));
        float d02 = 2.f*((px*pz + pw*py) - (gx*gz + gw*gy));
        float d10 = 2.f*((px*py + pw*pz) - (gx*gy + gw*gz));
        float d11 = 2.f*((gx*gx + gz*gz) - (px*px + pz*pz));
        float d12 = 2.f*((py*pz - pw*px) - (gy*gz - gw*gx));
        float d20 = 2.f*((px*pz - pw*py) - (gx*gz - gw*gy));
        float d21 = 2.f*((py*pz + pw*px) - (gy*gz + gw*gx));
        float d22 = 2.f*((gx*gx + gy*gy) - (px*px + py*py));

        float tdx = pred_t[3*b+0] - gt_t[3*b+0];
        float tdy = pred_t[3*b+1] - gt_t[3*b+1];
        float tdz = pred_t[3*b+2] - gt_t[3*b+2];

        const int obj = obj_ids[b];
        // object row = 1500 floats = 6000 B (16-divisible -> float4-aligned)
        const float4* __restrict__ P4 = (const float4*)(points + (size_t)obj * (NPTS*3));

        float s = 0.0f;
        // 500 points = 125 groups of 4 points (3 float4 per group).
        // Points processed as packed pairs (v2f) -> v_pk_fma_f32 / v_pk_add_f32.
        #pragma unroll
        for (int t = 0; t < 2; ++t) {
            const int g = t*64 + lane;
            if (t == 0 || lane < 61) {
                float4 a  = P4[3*g+0];
                float4 b4 = P4[3*g+1];
                float4 c  = P4[3*g+2];
                v2f xs[2] = { {a.x, a.w},  {b4.z, c.y} };
                v2f ys[2] = { {a.y, b4.x}, {b4.w, c.z} };
                v2f zs[2] = { {a.z, b4.y}, {c.x, c.w} };
                #pragma unroll
                for (int j = 0; j < 2; ++j) {
                    v2f x = xs[j], y = ys[j], z = zs[j];
                    v2f vx = d00*x + d01*y + d02*z;
                    v2f vy = d10*x + d11*y + d12*z;
                    v2f vz = d20*x + d21*y + d22*z;
                    v2f r  = vx*vx + vy*vy + vz*vz;
                    s += fsqrt(r.x) + fsqrt(r.y);
                    v2f ax = vx + tdx, ay = vy + tdy, az = vz + tdz;
                    v2f r2 = ax*ax + ay*ay + az*az;
                    s += fsqrt(r2.x) + fsqrt(r2.y);
                }
            }
        }

        acc_pts   += s;
        acc_trans += fsqrt(tdx*tdx + tdy*tdy + tdz*tdz);
    }

    // one butterfly per wave
    #pragma unroll
    for (int off = 32; off > 0; off >>= 1)
        acc_pts += __shfl_down(acc_pts, off, 64);

    __shared__ float red[WPB];
    if (lane == 0)
        red[wave] = acc_pts * (1.0f / NPTS) + acc_trans;
    __syncthreads();
    if (threadIdx.x == 0)
        partial[blockIdx.x] = red[0] + red[1] + red[2] + red[3];  // plain store, no contention
}

__global__ __launch_bounds__(256) void add_loss_stage2(
    const float* __restrict__ partial,  // (NBLK,)
    float* __restrict__ out)            // scalar
{
    const int wave = threadIdx.x >> 6;
    const int lane = threadIdx.x & 63;

    float s = 0.0f;
    #pragma unroll
    for (int k = 0; k < NBLK / 256; ++k)
        s += partial[k * 256 + threadIdx.x];

    #pragma unroll
    for (int off = 32; off > 0; off >>= 1)
        s += __shfl_down(s, off, 64);

    __shared__ float red[4];
    if (lane == 0) red[wave] = s;
    __syncthreads();
    if (threadIdx.x == 0)
        out[0] = (red[0] + red[1] + red[2] + red[3]) * (1.0f / BATCH);
}

extern "C" void kernel_launch(void* const* d_in, const int* in_sizes, int n_in,
                              void* d_out, int out_size, void* d_ws, size_t ws_size,
                              hipStream_t stream) {
    const float* pred_r  = (const float*)d_in[0];
    const float* pred_t  = (const float*)d_in[1];
    const float* gt_r    = (const float*)d_in[2];
    const float* gt_t    = (const float*)d_in[3];
    const int*   obj_ids = (const int*)d_in[4];
    const float* points  = (const float*)d_in[5];
    float* out     = (float*)d_out;
    float* partial = (float*)d_ws;      // 2048 floats = 8 KB of scratch

    add_loss_stage1<<<NBLK, 256, 0, stream>>>(
        pred_r, pred_t, gt_r, gt_t, obj_ids, points, partial);
    add_loss_stage2<<<1, 256, 0, stream>>>(partial, out);
}